// Round 2
// baseline (239.266 us; speedup 1.0000x reference)
//
#include <hip/hip_runtime.h>
#include <hip/hip_bf16.h>
#include <stdint.h>

// ---------------------------------------------------------------------------
// NRI-style MLP encoder. B=32, T=50, N=100, D=4, E=9900, H=256. fp32 I/O.
// R7 formulation (send terms are node GEMMs; only edge GEMM is K=256 t2@Wpz).
// R20 = R19 + phaseB VALU diet: closed-form j (no jtab LDS), wave-uniform
// branch for U-row select in stage0, 32-bit offset addressing on all hot
// global loads, pinned Vs/C4 prefetch (asm "+v" keeps loads hoisted above
// the K-loop), pointer-bump K-loop bases, f32 C4 selects in z4, no pad-row
// masking in stage0 (pad garbage only reaches masked output rows).
// Spill guard: WRITE_SIZE must stay ~4950 KB.
// Pipeline (4 dispatches): prep, nodeA, nodeC(+colsum), phaseB.
// ---------------------------------------------------------------------------

typedef __attribute__((ext_vector_type(8))) short short8;
typedef __attribute__((ext_vector_type(4))) float float4v;
typedef __attribute__((ext_vector_type(4))) unsigned short ushort4v;
typedef __attribute__((ext_vector_type(4))) unsigned int uint4v;
typedef __attribute__((ext_vector_type(2))) unsigned int uint2v;

__device__ inline float bf2f(unsigned short u) {
    union { unsigned int i; float f; } v; v.i = ((unsigned int)u) << 16; return v.f;
}

#if __has_builtin(__builtin_amdgcn_cvt_pk_bf16_f32)
typedef __attribute__((ext_vector_type(2))) __bf16 bf16x2;
__device__ inline unsigned int f2bf_pk(float a, float b) {   // [15:0]=a [31:16]=b
    union { bf16x2 v; unsigned int u; } c;
    c.v = __builtin_amdgcn_cvt_pk_bf16_f32(a, b);
    return c.u;
}
__device__ inline unsigned short f2bf(float f) {
    return (unsigned short)(f2bf_pk(f, f) & 0xFFFFu);
}
#else
__device__ inline unsigned short f2bf(float f) {
    union { float f; unsigned int i; } v; v.f = f;
    unsigned int i = v.i;
    return (unsigned short)((i + 0x7FFFu + ((i >> 16) & 1u)) >> 16);
}
__device__ inline unsigned int f2bf_pk(float a, float b) {
    return (unsigned int)f2bf(a) | ((unsigned int)f2bf(b) << 16);
}
#endif

// ---------------------------------------------------------------------------
// MEGA-PREP: bx<2272 weight packs | <2528 Wpz=pack(w2b@w4a_e, EVEN/ODD perm)
// | <2530 misc (Wfp/bfv/b4ap/b2bs) | rest repack x.
// ---------------------------------------------------------------------------
__global__ __launch_bounds__(256) void prep_kernel(
        const float* __restrict__ x,
        const float* __restrict__ w1a, const float* __restrict__ w1b,
        const float* __restrict__ w2a, const float* __restrict__ w2b,
        const float* __restrict__ w3a, const float* __restrict__ w3b,
        const float* __restrict__ w4a, const float* __restrict__ b4a,
        const float* __restrict__ w4b, const float* __restrict__ b4b,
        const float* __restrict__ wo,  const float* __restrict__ bo,
        const float* __restrict__ b2b,
        unsigned short* __restrict__ Wp1a, unsigned short* __restrict__ Wp1b,
        unsigned short* __restrict__ Wp2r, unsigned short* __restrict__ Wp2s,
        unsigned short* __restrict__ Wp2b, unsigned short* __restrict__ Wp3a,
        unsigned short* __restrict__ Wp3b, unsigned short* __restrict__ Wp4r,
        unsigned short* __restrict__ Wp4s, unsigned short* __restrict__ Wpz,
        unsigned short* __restrict__ Wfp, float* __restrict__ bfv,
        float* __restrict__ b4ap, float* __restrict__ b2bs,
        unsigned short* __restrict__ hin) {
    int bx = blockIdx.x;
    int tid = threadIdx.x;
    if (bx < 2272) {
        const float* W; unsigned short* Wp; int Kin; int b0;
        if      (bx <  224) { W = w1a;             Wp = Wp1a; Kin = 200; b0 = 0;    }
        else if (bx <  480) { W = w1b;             Wp = Wp1b; Kin = 256; b0 = 224;  }
        else if (bx <  736) { W = w2a;             Wp = Wp2r; Kin = 256; b0 = 480;  }
        else if (bx <  992) { W = w2a + 256 * 256; Wp = Wp2s; Kin = 256; b0 = 736;  }
        else if (bx < 1248) { W = w2b;             Wp = Wp2b; Kin = 256; b0 = 992;  }
        else if (bx < 1504) { W = w3a;             Wp = Wp3a; Kin = 256; b0 = 1248; }
        else if (bx < 1760) { W = w3b;             Wp = Wp3b; Kin = 256; b0 = 1504; }
        else if (bx < 2016) { W = w4a;             Wp = Wp4r; Kin = 256; b0 = 1760; }
        else                { W = w4a + 256 * 256; Wp = Wp4s; Kin = 256; b0 = 2016; }
        int idx = (bx - b0) * 256 + tid;
        int k = idx >> 8, n = idx & 255;
        unsigned short v = (k < Kin) ? f2bf(W[k * 256 + n]) : (unsigned short)0;
        Wp[((size_t)(k >> 5) * 256 + n) * 32 + (k & 31)] = v;
    } else if (bx < 2528) {
        int k = bx - 2272, c = tid;           // c = PHYSICAL output col
        float s = 0.f;
        for (int t = 0; t < 256; ++t)
            s += w2b[k * 256 + t] * w4a[(size_t)(512 + t) * 256 + c];
        // even/odd pairing: packed pos n = w*32 + (c&1)*16 + ((c&31)>>1)
        int n = (c & ~31) + (c & 1) * 16 + ((c & 31) >> 1);
        Wpz[((size_t)(k >> 5) * 256 + n) * 32 + (k & 31)] = f2bf(s);
    } else if (bx < 2530) {
        int k = tid;
        if (bx == 2528) {
            float a[4] = {0.f, 0.f, 0.f, 0.f};
            for (int c = 0; c < 256; ++c) {
                float wv = w4b[k * 256 + c];
                #pragma unroll
                for (int o = 0; o < 4; ++o) a[o] += wv * wo[c * 4 + o];
            }
            #pragma unroll
            for (int n = 0; n < 16; ++n)
                Wfp[(size_t)(k >> 5) * 512 + n * 32 + (k & 31)] =
                    (n < 4) ? f2bf(a[n]) : (unsigned short)0;
            if (k < 4) {
                float s = bo[k];
                for (int c = 0; c < 256; ++c) s += b4b[c] * wo[c * 4 + k];
                bfv[k] = s;
            }
        } else {
            float s = b4a[k];
            for (int t = 0; t < 256; ++t)
                s += b2b[t] * w4a[(size_t)(512 + t) * 256 + k];
            b4ap[k] = s;
            b2bs[k] = 0.99f * b2b[k];
        }
    } else {
        int idx = (bx - 2530) * 256 + tid;
        if (idx < 3200 * 224) {
            int row = idx / 224;
            int c = idx - row * 224;
            int b = row / 100, n = row - b * 100;
            unsigned short v = 0;
            if (c < 200) {
                int t = c >> 2, d = c & 3;
                v = f2bf(x[(((size_t)(b * 50 + t)) * 100 + n) * 4 + d]);
            }
            hin[(size_t)row * 224 + c] = v;
        }
    }
}

// ---------------------------------------------------------------------------
// nodeA (fused, 512 thr = 8 waves x 32 cols): rows m0=bx*16.
// t1=relu(hin@W1a+b1a) [LDS] -> h=t1@W1b+b1b [LDS] -> U,Hs (dual, global).
// ---------------------------------------------------------------------------
__global__ __launch_bounds__(512) void node_fusedA_kernel(
        const unsigned short* __restrict__ hin,
        const unsigned short* __restrict__ Wp1a, const float* __restrict__ b1a,
        const unsigned short* __restrict__ Wp1b, const float* __restrict__ b1b,
        const unsigned short* __restrict__ Wp2r, const float* __restrict__ b2a,
        const unsigned short* __restrict__ Wp2s,
        unsigned short* __restrict__ U, unsigned short* __restrict__ Hs) {
    __shared__ __align__(16) unsigned short t1s[16 * 264];
    __shared__ __align__(16) unsigned short hs2[16 * 264];
    const int m0 = blockIdx.x * 16;
    const int tid  = threadIdx.x;
    const int wave = tid >> 6;          // 0..7
    const int lane = tid & 63;
    const int l15  = lane & 15;
    const int quad = lane >> 4;
    const int n0   = wave * 32;
    const int koff = quad * 8;

    // ---- S1: t1 = relu(hin@W1a + b1a), K=224 ----
    {
        float4v acc[2];
        acc[0] = (float4v)(0.0f); acc[1] = (float4v)(0.0f);
        for (int kb = 0; kb < 7; ++kb) {
            short8 af = *(const short8*)(hin + (size_t)(m0 + l15) * 224 + kb * 32 + koff);
            #pragma unroll
            for (int ni = 0; ni < 2; ++ni) {
                short8 bf = *(const short8*)(Wp1a + ((size_t)kb * 256 + n0 + ni * 16 + l15) * 32 + koff);
                acc[ni] = __builtin_amdgcn_mfma_f32_16x16x32_bf16(af, bf, acc[ni], 0, 0, 0);
            }
        }
        #pragma unroll
        for (int ni = 0; ni < 2; ++ni) {
            int col = n0 + ni * 16 + l15;
            float bv = b1a[col];
            #pragma unroll
            for (int r = 0; r < 4; ++r) {
                float v = acc[ni][r] + bv;
                v = v > 0.f ? v : 0.f;
                t1s[(quad * 4 + r) * 264 + col] = f2bf(v);
            }
        }
    }
    __syncthreads();

    // ---- S2: h = t1@W1b + b1b ----
    {
        float4v acc[2];
        acc[0] = (float4v)(0.0f); acc[1] = (float4v)(0.0f);
        for (int kb = 0; kb < 8; ++kb) {
            short8 af = *(const short8*)(&t1s[l15 * 264 + kb * 32 + koff]);
            #pragma unroll
            for (int ni = 0; ni < 2; ++ni) {
                short8 bf = *(const short8*)(Wp1b + ((size_t)kb * 256 + n0 + ni * 16 + l15) * 32 + koff);
                acc[ni] = __builtin_amdgcn_mfma_f32_16x16x32_bf16(af, bf, acc[ni], 0, 0, 0);
            }
        }
        #pragma unroll
        for (int ni = 0; ni < 2; ++ni) {
            int col = n0 + ni * 16 + l15;
            float bv = b1b[col];
            #pragma unroll
            for (int r = 0; r < 4; ++r)
                hs2[(quad * 4 + r) * 264 + col] = f2bf(acc[ni][r] + bv);
        }
    }
    __syncthreads();

    // ---- S3 (dual): U = h@W2r + b2a ; Hs = h@W2s ----
    {
        float4v aU[2], aH[2];
        aU[0] = (float4v)(0.0f); aU[1] = (float4v)(0.0f);
        aH[0] = (float4v)(0.0f); aH[1] = (float4v)(0.0f);
        for (int kb = 0; kb < 8; ++kb) {
            short8 af = *(const short8*)(&hs2[l15 * 264 + kb * 32 + koff]);
            #pragma unroll
            for (int ni = 0; ni < 2; ++ni) {
                short8 bu = *(const short8*)(Wp2r + ((size_t)kb * 256 + n0 + ni * 16 + l15) * 32 + koff);
                short8 bh = *(const short8*)(Wp2s + ((size_t)kb * 256 + n0 + ni * 16 + l15) * 32 + koff);
                aU[ni] = __builtin_amdgcn_mfma_f32_16x16x32_bf16(af, bu, aU[ni], 0, 0, 0);
                aH[ni] = __builtin_amdgcn_mfma_f32_16x16x32_bf16(af, bh, aH[ni], 0, 0, 0);
            }
        }
        #pragma unroll
        for (int ni = 0; ni < 2; ++ni) {
            int col = n0 + ni * 16 + l15;
            float bv = b2a[col];
            #pragma unroll
            for (int r = 0; r < 4; ++r) {
                size_t o = (size_t)(m0 + quad * 4 + r) * 256 + col;
                U[o]  = f2bf(aU[ni][r] + bv);
                Hs[o] = f2bf(aH[ni][r]);
            }
        }
    }
}

// ---------------------------------------------------------------------------
// nodeC (fused + colsum S0, 512 thr): rows m0=bx*16.
// S0: Ssc -> buf1 [LDS]; S1: vin -> buf0; S2: t3 -> buf1; S3: v2 -> buf0;
// S4 (dual): C4, Vs -> global.
// ---------------------------------------------------------------------------
__global__ __launch_bounds__(512) void node_fusedC_kernel(
        const unsigned short* __restrict__ U, const unsigned short* __restrict__ Hs,
        const unsigned short* __restrict__ Wp2b, const float* __restrict__ b2bs,
        const unsigned short* __restrict__ Wp3a, const float* __restrict__ b3a,
        const unsigned short* __restrict__ Wp3b, const float* __restrict__ b3b,
        const unsigned short* __restrict__ Wp4r, const float* __restrict__ b4ap,
        const unsigned short* __restrict__ Wp4s,
        unsigned short* __restrict__ C4, unsigned short* __restrict__ Vs) {
    __shared__ __align__(16) unsigned short buf0[16 * 264];
    __shared__ __align__(16) unsigned short buf1[16 * 264];
    const int m0 = blockIdx.x * 16;
    const int tid  = threadIdx.x;
    const int wave = tid >> 6;
    const int lane = tid & 63;
    const int l15  = lane & 15;
    const int quad = lane >> 4;
    const int n0   = wave * 32;
    const int koff = quad * 8;

    // ---- S0: colsum -> buf1 (Ssc rows local 0..15) ----
    {
        const int rl = tid >> 5;           // group 0..15
        const int ct = (tid & 31) * 8;     // 8 cols
        const int g = m0 + rl;
        const int b = g / 100, i = g - b * 100;
        float u[8], s[8];
        {
            ushort4v u0 = *(const ushort4v*)(U + (size_t)g * 256 + ct);
            ushort4v u1 = *(const ushort4v*)(U + (size_t)g * 256 + ct + 4);
            #pragma unroll
            for (int e = 0; e < 4; ++e) { u[e] = bf2f(u0[e]); u[4 + e] = bf2f(u1[e]); }
            #pragma unroll
            for (int e = 0; e < 8; ++e) s[e] = 0.f;
        }
        const unsigned short* base = Hs + (size_t)b * 100 * 256 + ct;
        #pragma unroll 5
        for (int j = 0; j < 100; ++j) {
            ushort4v h0 = *(const ushort4v*)(base + (size_t)j * 256);
            ushort4v h1 = *(const ushort4v*)(base + (size_t)j * 256 + 4);
            #pragma unroll
            for (int e = 0; e < 4; ++e) {
                float v0 = u[e] + bf2f(h0[e]);     s[e]     += (v0 > 0.f ? v0 : 0.f);
                float v1 = u[4 + e] + bf2f(h1[e]); s[4 + e] += (v1 > 0.f ? v1 : 0.f);
            }
        }
        {
            ushort4v h0 = *(const ushort4v*)(base + (size_t)i * 256);
            ushort4v h1 = *(const ushort4v*)(base + (size_t)i * 256 + 4);
            #pragma unroll
            for (int e = 0; e < 4; ++e) {
                float v0 = u[e] + bf2f(h0[e]);     s[e]     -= (v0 > 0.f ? v0 : 0.f);
                float v1 = u[4 + e] + bf2f(h1[e]); s[4 + e] -= (v1 > 0.f ? v1 : 0.f);
            }
        }
        uint4v d;
        d[0] = f2bf_pk(s[0] * 0.01f, s[1] * 0.01f);
        d[1] = f2bf_pk(s[2] * 0.01f, s[3] * 0.01f);
        d[2] = f2bf_pk(s[4] * 0.01f, s[5] * 0.01f);
        d[3] = f2bf_pk(s[6] * 0.01f, s[7] * 0.01f);
        *(uint4v*)(&buf1[rl * 264 + ct]) = d;
    }
    __syncthreads();

    // ---- S1: vin = Ssc@W2b + b2bs -> buf0 ----
    {
        float4v acc[2];
        acc[0] = (float4v)(0.0f); acc[1] = (float4v)(0.0f);
        for (int kb = 0; kb < 8; ++kb) {
            short8 af = *(const short8*)(&buf1[l15 * 264 + kb * 32 + koff]);
            #pragma unroll
            for (int ni = 0; ni < 2; ++ni) {
                short8 bf = *(const short8*)(Wp2b + ((size_t)kb * 256 + n0 + ni * 16 + l15) * 32 + koff);
                acc[ni] = __builtin_amdgcn_mfma_f32_16x16x32_bf16(af, bf, acc[ni], 0, 0, 0);
            }
        }
        #pragma unroll
        for (int ni = 0; ni < 2; ++ni) {
            int col = n0 + ni * 16 + l15;
            float bv = b2bs[col];
            #pragma unroll
            for (int r = 0; r < 4; ++r)
                buf0[(quad * 4 + r) * 264 + col] = f2bf(acc[ni][r] + bv);
        }
    }
    __syncthreads();

    // ---- S2: t3 = relu(vin@W3a + b3a) -> buf1 ----
    {
        float4v acc[2];
        acc[0] = (float4v)(0.0f); acc[1] = (float4v)(0.0f);
        for (int kb = 0; kb < 8; ++kb) {
            short8 af = *(const short8*)(&buf0[l15 * 264 + kb * 32 + koff]);
            #pragma unroll
            for (int ni = 0; ni < 2; ++ni) {
                short8 bf = *(const short8*)(Wp3a + ((size_t)kb * 256 + n0 + ni * 16 + l15) * 32 + koff);
                acc[ni] = __builtin_amdgcn_mfma_f32_16x16x32_bf16(af, bf, acc[ni], 0, 0, 0);
            }
        }
        __syncthreads();   // buf1's S1 readers done; safe rewrite
        #pragma unroll
        for (int ni = 0; ni < 2; ++ni) {
            int col = n0 + ni * 16 + l15;
            float bv = b3a[col];
            #pragma unroll
            for (int r = 0; r < 4; ++r) {
                float v = acc[ni][r] + bv;
                v = v > 0.f ? v : 0.f;
                buf1[(quad * 4 + r) * 264 + col] = f2bf(v);
            }
        }
    }
    __syncthreads();

    // ---- S3: v2 = t3@W3b + b3b -> buf0 ----
    {
        float4v acc[2];
        acc[0] = (float4v)(0.0f); acc[1] = (float4v)(0.0f);
        for (int kb = 0; kb < 8; ++kb) {
            short8 af = *(const short8*)(&buf1[l15 * 264 + kb * 32 + koff]);
            #pragma unroll
            for (int ni = 0; ni < 2; ++ni) {
                short8 bf = *(const short8*)(Wp3b + ((size_t)kb * 256 + n0 + ni * 16 + l15) * 32 + koff);
                acc[ni] = __builtin_amdgcn_mfma_f32_16x16x32_bf16(af, bf, acc[ni], 0, 0, 0);
            }
        }
        __syncthreads();   // buf0's S2 readers done; safe rewrite
        #pragma unroll
        for (int ni = 0; ni < 2; ++ni) {
            int col = n0 + ni * 16 + l15;
            float bv = b3b[col];
            #pragma unroll
            for (int r = 0; r < 4; ++r)
                buf0[(quad * 4 + r) * 264 + col] = f2bf(acc[ni][r] + bv);
        }
    }
    __syncthreads();

    // ---- S4 (dual): C4 = v2@W4r + b4ap ; Vs = v2@W4s ----
    {
        float4v aC[2], aV[2];
        aC[0] = (float4v)(0.0f); aC[1] = (float4v)(0.0f);
        aV[0] = (float4v)(0.0f); aV[1] = (float4v)(0.0f);
        for (int kb = 0; kb < 8; ++kb) {
            short8 af = *(const short8*)(&buf0[l15 * 264 + kb * 32 + koff]);
            #pragma unroll
            for (int ni = 0; ni < 2; ++ni) {
                short8 bc = *(const short8*)(Wp4r + ((size_t)kb * 256 + n0 + ni * 16 + l15) * 32 + koff);
                short8 bv = *(const short8*)(Wp4s + ((size_t)kb * 256 + n0 + ni * 16 + l15) * 32 + koff);
                aC[ni] = __builtin_amdgcn_mfma_f32_16x16x32_bf16(af, bc, aC[ni], 0, 0, 0);
                aV[ni] = __builtin_amdgcn_mfma_f32_16x16x32_bf16(af, bv, aV[ni], 0, 0, 0);
            }
        }
        #pragma unroll
        for (int ni = 0; ni < 2; ++ni) {
            int col = n0 + ni * 16 + l15;
            float bv = b4ap[col];
            #pragma unroll
            for (int r = 0; r < 4; ++r) {
                size_t o = (size_t)(m0 + quad * 4 + r) * 256 + col;
                C4[o] = f2bf(aC[ni][r] + bv);
                Vs[o] = f2bf(aV[ni][r]);
            }
        }
    }
}

// ---------------------------------------------------------------------------
// Phase B: grid (155,32), block 512 (8 waves x 32 cols, EVEN/ODD pairing).
// EDGE-LINEAR + VALU diet. Block (t,b) owns flat edges e0=t*64..+63 of batch
// b; nr spans <=2 values (split row br). stage0: wave-uniform row loop, scalar
// j, uniform U-row branch, no pad masking. Prefetch: closed-form j, 16 Vs
// dwords + C4 unpacked to f32, pinned via asm before K-loop. K-loop: acc[4][2]
// vs permuted Wpz, pointer-bump bases, UNROLL 2. z4: f32 C4 selects, reg-only.
// Projection waves 0-3 vs Wfp. LDS 33792 B. (512,6). Spill guard ~4950 KB.
// ---------------------------------------------------------------------------
__global__ __launch_bounds__(512, 6) void edge_phaseB_kernel(
        const unsigned short* __restrict__ Hs, const unsigned short* __restrict__ Vs,
        const unsigned short* __restrict__ U, const unsigned short* __restrict__ C4,
        const unsigned short* __restrict__ Wpz, const unsigned short* __restrict__ Wfp,
        const float* __restrict__ bfv,
        float* __restrict__ out) {
    __shared__ __align__(16) unsigned short t2s[64 * 264]; // 33792 B (z4 aliases later)
    const int e0 = blockIdx.x * 64;           // first flat edge of tile
    const int b  = blockIdx.y;
    const int nE = (9900 - e0) < 64 ? (9900 - e0) : 64;   // 64 (or 44 last tile)
    const int nr0 = e0 / 99;                  // receiver of first edge
    const int nr1c = (nr0 < 99) ? nr0 + 1 : 99;           // clamped (load safety)
    const int br  = (nr0 + 1) * 99 - e0;      // local row where receiver -> nr1
    const unsigned ub100 = (unsigned)(b * 100);
    const int tid  = threadIdx.x;
    const int wave = tid >> 6;          // 0..7
    const int lane = tid & 63;
    const int l15  = lane & 15;
    const int quad = lane >> 4;
    const int n0   = wave * 32;         // 32-col slice per wave
    const int koff = quad * 8;

    // ---- stage 0: build t2 tile (8 rows/wave; wave-uniform j + U branch) ----
    {
        const int c = lane * 4;
        ushort4v uva = *(const ushort4v*)(U + (((unsigned)(ub100 + (unsigned)nr0)) << 8) + c);
        ushort4v uvb = *(const ushort4v*)(U + (((unsigned)(ub100 + (unsigned)nr1c)) << 8) + c);
        float ua0 = bf2f(uva[0]), ua1 = bf2f(uva[1]), ua2 = bf2f(uva[2]), ua3 = bf2f(uva[3]);
        float ub0 = bf2f(uvb[0]), ub1 = bf2f(uvb[1]), ub2 = bf2f(uvb[2]), ub3 = bf2f(uvb[3]);
        for (int r = wave; r < 64; r += 8) {
            // wave-uniform scalar math:
            int sec = (r >= br) ? 1 : 0;
            int nr  = nr0 + sec;
            int k   = e0 + r - nr * 99;
            int j   = k + (k >= nr ? 1 : 0);
            ushort4v hv = *(const ushort4v*)(Hs + ((ub100 + (unsigned)j) << 8) + c);
            float t0, t1, t2, t3;
            if (sec) {            // wave-uniform branch, no cndmask
                t0 = ub0 + bf2f(hv[0]); t1 = ub1 + bf2f(hv[1]);
                t2 = ub2 + bf2f(hv[2]); t3 = ub3 + bf2f(hv[3]);
            } else {
                t0 = ua0 + bf2f(hv[0]); t1 = ua1 + bf2f(hv[1]);
                t2 = ua2 + bf2f(hv[2]); t3 = ua3 + bf2f(hv[3]);
            }
            t0 = t0 > 0.f ? t0 : 0.f;
            t1 = t1 > 0.f ? t1 : 0.f;
            t2 = t2 > 0.f ? t2 : 0.f;
            t3 = t3 > 0.f ? t3 : 0.f;
            uint2v p;
            p[0] = f2bf_pk(t0, t1);
            p[1] = f2bf_pk(t2, t3);
            *(uint2v*)(&t2s[r * 264 + c]) = p;
        }
    }
    __syncthreads();

    // ---- prefetch: 16 Vs dwords (closed-form j) + C4 as f32, pinned ----
    const int cp = n0 + 2 * l15;            // even col; odd = cp+1
    const int rbase = quad * 4;             // this thread's row offset within mi-tile
    unsigned int vsp[16];
    #pragma unroll
    for (int mi = 0; mi < 4; ++mi) {
        #pragma unroll
        for (int r = 0; r < 4; ++r) {
            int row = mi * 16 + rbase + r;
            int sec = (row >= br) ? 1 : 0;
            int nr  = nr0 + sec;
            int k   = e0 + row - nr * 99;
            int j   = k + (k >= nr ? 1 : 0);
            vsp[mi * 4 + r] =
                *(const unsigned int*)(Vs + ((ub100 + (unsigned)j) << 8) + (unsigned)cp);
        }
    }
    unsigned int c4a = *(const unsigned int*)(C4 + ((ub100 + (unsigned)nr0) << 8) + (unsigned)cp);
    unsigned int c4b = *(const unsigned int*)(C4 + ((ub100 + (unsigned)nr1c) << 8) + (unsigned)cp);
    float c4e0 = bf2f((unsigned short)c4a);
    float c4o0 = bf2f((unsigned short)(c4a >> 16));
    float c4e1 = bf2f((unsigned short)c4b);
    float c4o1 = bf2f((unsigned short)(c4b >> 16));
    #pragma unroll
    for (int i = 0; i < 16; ++i) asm volatile("" : "+v"(vsp[i]));   // pin above K-loop
    asm volatile("" : "+v"(c4e0), "+v"(c4o0), "+v"(c4e1), "+v"(c4o1));

    // ---- K-loop: z4 GEMM (K=256); acc init = 0 (C4 added in z4) ----
    float4v acc[4][2];
    #pragma unroll
    for (int mi = 0; mi < 4; ++mi) {
        acc[mi][0] = (float4v)(0.0f);
        acc[mi][1] = (float4v)(0.0f);
    }

    const unsigned short* wz = Wpz + (((unsigned)(n0 + l15)) << 5) + (unsigned)koff;
    const unsigned short* a0 = t2s + l15 * 264 + koff;
    #pragma unroll 2              // acc=32 regs; 2-iter live window fits ~85 cap
    for (int kb = 0; kb < 8; ++kb) {
        short8 bf0 = *(const short8*)(wz);
        short8 bf1 = *(const short8*)(wz + 512);     // +16 packed cols
        #pragma unroll
        for (int mi = 0; mi < 4; ++mi) {
            short8 af = *(const short8*)(a0 + mi * 16 * 264 + kb * 32);
            acc[mi][0] = __builtin_amdgcn_mfma_f32_16x16x32_bf16(af, bf0, acc[mi][0], 0, 0, 0);
            acc[mi][1] = __builtin_amdgcn_mfma_f32_16x16x32_bf16(af, bf1, acc[mi][1], 0, 0, 0);
        }
        wz += 8192;               // next K-block (256 packed cols * 32)
    }
    __syncthreads();            // all t2s A-reads done; z4 aliases t2s below

    // ---- z4 = relu(C4_nr + Vs_j + acc) -> LDS (natural order, reg-only) ----
    #pragma unroll
    for (int mi = 0; mi < 4; ++mi) {
        #pragma unroll
        for (int r = 0; r < 4; ++r) {
            int row = mi * 16 + rbase + r;      // local edge idx (C-layout)
            unsigned int vp = vsp[mi * 4 + r];
            float ce = (row >= br) ? c4e1 : c4e0;
            float co = (row >= br) ? c4o1 : c4o0;
            float z0 = bf2f((unsigned short)vp) + ce + acc[mi][0][r];
            float z1 = bf2f((unsigned short)(vp >> 16)) + co + acc[mi][1][r];
            z0 = z0 > 0.f ? z0 : 0.f;
            z1 = z1 > 0.f ? z1 : 0.f;
            *(unsigned int*)(&t2s[row * 264 + cp]) = f2bf_pk(z0, z1);
        }
    }
    __syncthreads();

    // ---- projection: waves 0-3, rows wave*16..+15; 8 MFMA vs Wfp ----
    if (wave < 4) {
        float4v pacc = (float4v)(0.0f);
        const unsigned short* za0 = t2s + (wave * 16 + l15) * 264 + koff;
        const unsigned short* wf0 = Wfp + (unsigned)(l15 * 32 + koff);
        #pragma unroll
        for (int kb = 0; kb < 8; ++kb) {
            short8 za = *(const short8*)(za0 + kb * 32);
            short8 wb = *(const short8*)(wf0 + kb * 512);
            pacc = __builtin_amdgcn_mfma_f32_16x16x32_bf16(za, wb, pacc, 0, 0, 0);
        }
        if (l15 < 4) {
            float bv = bfv[l15];
            #pragma unroll
            for (int r = 0; r < 4; ++r) {
                int row = wave * 16 + rbase + r;
                if (row < nE)
                    out[(unsigned)((b * 9900 + e0 + row) * 4 + l15)] = pacc[r] + bv;
            }
        }
    }
}

extern "C" void kernel_launch(void* const* d_in, const int* in_sizes, int n_in,
                              void* d_out, int out_size, void* d_ws, size_t ws_size,
                              hipStream_t stream) {
    const float* x   = (const float*)d_in[0];
    const float* w1a = (const float*)d_in[3];
    const float* b1a = (const float*)d_in[4];
    const float* w1b = (const float*)d_in[5];
    const float* b1b = (const float*)d_in[6];
    const float* w2a = (const float*)d_in[7];
    const float* b2a = (const float*)d_in[8];
    const float* w2b = (const float*)d_in[9];
    const float* b2b = (const float*)d_in[10];
    const float* w3a = (const float*)d_in[11];
    const float* b3a = (const float*)d_in[12];
    const float* w3b = (const float*)d_in[13];
    const float* b3b = (const float*)d_in[14];
    const float* w4a = (const float*)d_in[15];
    const float* b4a = (const float*)d_in[16];
    const float* w4b = (const float*)d_in[17];
    const float* b4b = (const float*)d_in[18];
    const float* wo  = (const float*)d_in[19];
    const float* bo  = (const float*)d_in[20];
    float* out = (float*)d_out;
    (void)in_sizes; (void)n_in; (void)out_size; (void)ws_size;

    char* ws = (char*)d_ws;
    size_t off = 0;
    auto alloc = [&](size_t bytes) {
        size_t o = off;
        off = (off + bytes + 255) & ~(size_t)255;
        return o;
    };
    const size_t SLOT_BF = (size_t)3200 * 256 * 2;   // 1.64 MB
    unsigned short* S_U  = (unsigned short*)(ws + alloc(SLOT_BF)); // U
    unsigned short* S_Hs = (unsigned short*)(ws + alloc(SLOT_BF)); // Hs
    unsigned short* S_Vs = (unsigned short*)(ws + alloc(SLOT_BF)); // Vs
    unsigned short* S_4  = (unsigned short*)(ws + alloc(SLOT_BF)); // hin -> C4
    unsigned short* Wp1a = (unsigned short*)(ws + alloc(224 * 256 * 2));
    unsigned short* Wp1b = (unsigned short*)(ws + alloc(256 * 256 * 2));
    unsigned short* Wp2r = (unsigned short*)(ws + alloc(256 * 256 * 2));
    unsigned short* Wp2s = (unsigned short*)(ws + alloc(256 * 256 * 2));
    unsigned short* Wp2b = (unsigned short*)(ws + alloc(256 * 256 * 2));
    unsigned short* Wp3a = (unsigned short*)(ws + alloc(256 * 256 * 2));
    unsigned short* Wp3b = (unsigned short*)(ws + alloc(256 * 256 * 2));
    unsigned short* Wp4r = (unsigned short*)(ws + alloc(256 * 256 * 2));
    unsigned short* Wp4s = (unsigned short*)(ws + alloc(256 * 256 * 2));
    unsigned short* Wpz  = (unsigned short*)(ws + alloc(256 * 256 * 2));
    unsigned short* Wfp  = (unsigned short*)(ws + alloc(8 * 16 * 32 * 2));
    float*          bfv  = (float*)(ws + alloc(4 * 4));
    float*          b4ap = (float*)(ws + alloc(256 * 4));
    float*          b2bs = (float*)(ws + alloc(256 * 4));
    // total ~8 MB (<= 11.2 proven safe)

    unsigned short* hin = S_4;   // [prep, nodeA]
    unsigned short* C4  = S_4;   // [nodeC, phaseB]

    // ---- 4 dispatches ----
    hipLaunchKernelGGL(prep_kernel, dim3(5330), dim3(256), 0, stream,
                       x, w1a, w1b, w2a, w2b, w3a, w3b, w4a, b4a, w4b, b4b, wo, bo, b2b,
                       Wp1a, Wp1b, Wp2r, Wp2s, Wp2b, Wp3a, Wp3b, Wp4r, Wp4s, Wpz,
                       Wfp, bfv, b4ap, b2bs, hin);
    hipLaunchKernelGGL(node_fusedA_kernel, dim3(200), dim3(512), 0, stream,
                       hin, Wp1a, b1a, Wp1b, b1b, Wp2r, b2a, Wp2s, S_U, S_Hs);
    hipLaunchKernelGGL(node_fusedC_kernel, dim3(200), dim3(512), 0, stream,
                       S_U, S_Hs, Wp2b, b2bs, Wp3a, b3a, Wp3b, b3b, Wp4r, b4ap, Wp4s, C4, S_Vs);
    hipLaunchKernelGGL(edge_phaseB_kernel, dim3(155, 32), dim3(512), 0, stream,
                       S_Hs, S_Vs, S_U, C4, Wpz, Wfp, bfv, out);
}

// Round 3
// 238.119 us; speedup vs baseline: 1.0048x; 1.0048x over previous
//
#include <hip/hip_runtime.h>
#include <hip/hip_bf16.h>
#include <stdint.h>

// ---------------------------------------------------------------------------
// NRI-style MLP encoder. B=32, T=50, N=100, D=4, E=9900, H=256. fp32 I/O.
// R7 formulation (send terms are node GEMMs; only edge GEMM is K=256 t2@Wpz).
// R21 = R19/R20 hybrid: EDGE-LINEAR tiling, NO asm pinning (R20's pin caused
// 2.1MB scratch spill: WRITE_SIZE 4950->7069KB), Vs/C4 prefetch hoisted
// BEFORE stage0 (syncthreads is a compiler fence -> loads drain at stage0's
// barrier, latency hidden under stage0's Hs reads), threshold-form j:
// j(row) = jb + row - 100*(row>=br) + (row>=bd0) + (row>=bd1), all block-
// uniform thresholds (3 cnd-adds/row, no mul). 32-bit addressing, pointer-
// bump K-loop. Spill guard: WRITE_SIZE must be ~4950 KB.
// Pipeline (4 dispatches): prep, nodeA, nodeC(+colsum), phaseB.
// ---------------------------------------------------------------------------

typedef __attribute__((ext_vector_type(8))) short short8;
typedef __attribute__((ext_vector_type(4))) float float4v;
typedef __attribute__((ext_vector_type(4))) unsigned short ushort4v;
typedef __attribute__((ext_vector_type(4))) unsigned int uint4v;
typedef __attribute__((ext_vector_type(2))) unsigned int uint2v;

__device__ inline float bf2f(unsigned short u) {
    union { unsigned int i; float f; } v; v.i = ((unsigned int)u) << 16; return v.f;
}

#if __has_builtin(__builtin_amdgcn_cvt_pk_bf16_f32)
typedef __attribute__((ext_vector_type(2))) __bf16 bf16x2;
__device__ inline unsigned int f2bf_pk(float a, float b) {   // [15:0]=a [31:16]=b
    union { bf16x2 v; unsigned int u; } c;
    c.v = __builtin_amdgcn_cvt_pk_bf16_f32(a, b);
    return c.u;
}
__device__ inline unsigned short f2bf(float f) {
    return (unsigned short)(f2bf_pk(f, f) & 0xFFFFu);
}
#else
__device__ inline unsigned short f2bf(float f) {
    union { float f; unsigned int i; } v; v.f = f;
    unsigned int i = v.i;
    return (unsigned short)((i + 0x7FFFu + ((i >> 16) & 1u)) >> 16);
}
__device__ inline unsigned int f2bf_pk(float a, float b) {
    return (unsigned int)f2bf(a) | ((unsigned int)f2bf(b) << 16);
}
#endif

// ---------------------------------------------------------------------------
// MEGA-PREP: bx<2272 weight packs | <2528 Wpz=pack(w2b@w4a_e, EVEN/ODD perm)
// | <2530 misc (Wfp/bfv/b4ap/b2bs) | rest repack x.
// ---------------------------------------------------------------------------
__global__ __launch_bounds__(256) void prep_kernel(
        const float* __restrict__ x,
        const float* __restrict__ w1a, const float* __restrict__ w1b,
        const float* __restrict__ w2a, const float* __restrict__ w2b,
        const float* __restrict__ w3a, const float* __restrict__ w3b,
        const float* __restrict__ w4a, const float* __restrict__ b4a,
        const float* __restrict__ w4b, const float* __restrict__ b4b,
        const float* __restrict__ wo,  const float* __restrict__ bo,
        const float* __restrict__ b2b,
        unsigned short* __restrict__ Wp1a, unsigned short* __restrict__ Wp1b,
        unsigned short* __restrict__ Wp2r, unsigned short* __restrict__ Wp2s,
        unsigned short* __restrict__ Wp2b, unsigned short* __restrict__ Wp3a,
        unsigned short* __restrict__ Wp3b, unsigned short* __restrict__ Wp4r,
        unsigned short* __restrict__ Wp4s, unsigned short* __restrict__ Wpz,
        unsigned short* __restrict__ Wfp, float* __restrict__ bfv,
        float* __restrict__ b4ap, float* __restrict__ b2bs,
        unsigned short* __restrict__ hin) {
    int bx = blockIdx.x;
    int tid = threadIdx.x;
    if (bx < 2272) {
        const float* W; unsigned short* Wp; int Kin; int b0;
        if      (bx <  224) { W = w1a;             Wp = Wp1a; Kin = 200; b0 = 0;    }
        else if (bx <  480) { W = w1b;             Wp = Wp1b; Kin = 256; b0 = 224;  }
        else if (bx <  736) { W = w2a;             Wp = Wp2r; Kin = 256; b0 = 480;  }
        else if (bx <  992) { W = w2a + 256 * 256; Wp = Wp2s; Kin = 256; b0 = 736;  }
        else if (bx < 1248) { W = w2b;             Wp = Wp2b; Kin = 256; b0 = 992;  }
        else if (bx < 1504) { W = w3a;             Wp = Wp3a; Kin = 256; b0 = 1248; }
        else if (bx < 1760) { W = w3b;             Wp = Wp3b; Kin = 256; b0 = 1504; }
        else if (bx < 2016) { W = w4a;             Wp = Wp4r; Kin = 256; b0 = 1760; }
        else                { W = w4a + 256 * 256; Wp = Wp4s; Kin = 256; b0 = 2016; }
        int idx = (bx - b0) * 256 + tid;
        int k = idx >> 8, n = idx & 255;
        unsigned short v = (k < Kin) ? f2bf(W[k * 256 + n]) : (unsigned short)0;
        Wp[((size_t)(k >> 5) * 256 + n) * 32 + (k & 31)] = v;
    } else if (bx < 2528) {
        int k = bx - 2272, c = tid;           // c = PHYSICAL output col
        float s = 0.f;
        for (int t = 0; t < 256; ++t)
            s += w2b[k * 256 + t] * w4a[(size_t)(512 + t) * 256 + c];
        // even/odd pairing: packed pos n = w*32 + (c&1)*16 + ((c&31)>>1)
        int n = (c & ~31) + (c & 1) * 16 + ((c & 31) >> 1);
        Wpz[((size_t)(k >> 5) * 256 + n) * 32 + (k & 31)] = f2bf(s);
    } else if (bx < 2530) {
        int k = tid;
        if (bx == 2528) {
            float a[4] = {0.f, 0.f, 0.f, 0.f};
            for (int c = 0; c < 256; ++c) {
                float wv = w4b[k * 256 + c];
                #pragma unroll
                for (int o = 0; o < 4; ++o) a[o] += wv * wo[c * 4 + o];
            }
            #pragma unroll
            for (int n = 0; n < 16; ++n)
                Wfp[(size_t)(k >> 5) * 512 + n * 32 + (k & 31)] =
                    (n < 4) ? f2bf(a[n]) : (unsigned short)0;
            if (k < 4) {
                float s = bo[k];
                for (int c = 0; c < 256; ++c) s += b4b[c] * wo[c * 4 + k];
                bfv[k] = s;
            }
        } else {
            float s = b4a[k];
            for (int t = 0; t < 256; ++t)
                s += b2b[t] * w4a[(size_t)(512 + t) * 256 + k];
            b4ap[k] = s;
            b2bs[k] = 0.99f * b2b[k];
        }
    } else {
        int idx = (bx - 2530) * 256 + tid;
        if (idx < 3200 * 224) {
            int row = idx / 224;
            int c = idx - row * 224;
            int b = row / 100, n = row - b * 100;
            unsigned short v = 0;
            if (c < 200) {
                int t = c >> 2, d = c & 3;
                v = f2bf(x[(((size_t)(b * 50 + t)) * 100 + n) * 4 + d]);
            }
            hin[(size_t)row * 224 + c] = v;
        }
    }
}

// ---------------------------------------------------------------------------
// nodeA (fused, 512 thr = 8 waves x 32 cols): rows m0=bx*16.
// t1=relu(hin@W1a+b1a) [LDS] -> h=t1@W1b+b1b [LDS] -> U,Hs (dual, global).
// ---------------------------------------------------------------------------
__global__ __launch_bounds__(512) void node_fusedA_kernel(
        const unsigned short* __restrict__ hin,
        const unsigned short* __restrict__ Wp1a, const float* __restrict__ b1a,
        const unsigned short* __restrict__ Wp1b, const float* __restrict__ b1b,
        const unsigned short* __restrict__ Wp2r, const float* __restrict__ b2a,
        const unsigned short* __restrict__ Wp2s,
        unsigned short* __restrict__ U, unsigned short* __restrict__ Hs) {
    __shared__ __align__(16) unsigned short t1s[16 * 264];
    __shared__ __align__(16) unsigned short hs2[16 * 264];
    const int m0 = blockIdx.x * 16;
    const int tid  = threadIdx.x;
    const int wave = tid >> 6;          // 0..7
    const int lane = tid & 63;
    const int l15  = lane & 15;
    const int quad = lane >> 4;
    const int n0   = wave * 32;
    const int koff = quad * 8;

    // ---- S1: t1 = relu(hin@W1a + b1a), K=224 ----
    {
        float4v acc[2];
        acc[0] = (float4v)(0.0f); acc[1] = (float4v)(0.0f);
        for (int kb = 0; kb < 7; ++kb) {
            short8 af = *(const short8*)(hin + (size_t)(m0 + l15) * 224 + kb * 32 + koff);
            #pragma unroll
            for (int ni = 0; ni < 2; ++ni) {
                short8 bf = *(const short8*)(Wp1a + ((size_t)kb * 256 + n0 + ni * 16 + l15) * 32 + koff);
                acc[ni] = __builtin_amdgcn_mfma_f32_16x16x32_bf16(af, bf, acc[ni], 0, 0, 0);
            }
        }
        #pragma unroll
        for (int ni = 0; ni < 2; ++ni) {
            int col = n0 + ni * 16 + l15;
            float bv = b1a[col];
            #pragma unroll
            for (int r = 0; r < 4; ++r) {
                float v = acc[ni][r] + bv;
                v = v > 0.f ? v : 0.f;
                t1s[(quad * 4 + r) * 264 + col] = f2bf(v);
            }
        }
    }
    __syncthreads();

    // ---- S2: h = t1@W1b + b1b ----
    {
        float4v acc[2];
        acc[0] = (float4v)(0.0f); acc[1] = (float4v)(0.0f);
        for (int kb = 0; kb < 8; ++kb) {
            short8 af = *(const short8*)(&t1s[l15 * 264 + kb * 32 + koff]);
            #pragma unroll
            for (int ni = 0; ni < 2; ++ni) {
                short8 bf = *(const short8*)(Wp1b + ((size_t)kb * 256 + n0 + ni * 16 + l15) * 32 + koff);
                acc[ni] = __builtin_amdgcn_mfma_f32_16x16x32_bf16(af, bf, acc[ni], 0, 0, 0);
            }
        }
        #pragma unroll
        for (int ni = 0; ni < 2; ++ni) {
            int col = n0 + ni * 16 + l15;
            float bv = b1b[col];
            #pragma unroll
            for (int r = 0; r < 4; ++r)
                hs2[(quad * 4 + r) * 264 + col] = f2bf(acc[ni][r] + bv);
        }
    }
    __syncthreads();

    // ---- S3 (dual): U = h@W2r + b2a ; Hs = h@W2s ----
    {
        float4v aU[2], aH[2];
        aU[0] = (float4v)(0.0f); aU[1] = (float4v)(0.0f);
        aH[0] = (float4v)(0.0f); aH[1] = (float4v)(0.0f);
        for (int kb = 0; kb < 8; ++kb) {
            short8 af = *(const short8*)(&hs2[l15 * 264 + kb * 32 + koff]);
            #pragma unroll
            for (int ni = 0; ni < 2; ++ni) {
                short8 bu = *(const short8*)(Wp2r + ((size_t)kb * 256 + n0 + ni * 16 + l15) * 32 + koff);
                short8 bh = *(const short8*)(Wp2s + ((size_t)kb * 256 + n0 + ni * 16 + l15) * 32 + koff);
                aU[ni] = __builtin_amdgcn_mfma_f32_16x16x32_bf16(af, bu, aU[ni], 0, 0, 0);
                aH[ni] = __builtin_amdgcn_mfma_f32_16x16x32_bf16(af, bh, aH[ni], 0, 0, 0);
            }
        }
        #pragma unroll
        for (int ni = 0; ni < 2; ++ni) {
            int col = n0 + ni * 16 + l15;
            float bv = b2a[col];
            #pragma unroll
            for (int r = 0; r < 4; ++r) {
                size_t o = (size_t)(m0 + quad * 4 + r) * 256 + col;
                U[o]  = f2bf(aU[ni][r] + bv);
                Hs[o] = f2bf(aH[ni][r]);
            }
        }
    }
}

// ---------------------------------------------------------------------------
// nodeC (fused + colsum S0, 512 thr): rows m0=bx*16.
// S0: Ssc -> buf1 [LDS]; S1: vin -> buf0; S2: t3 -> buf1; S3: v2 -> buf0;
// S4 (dual): C4, Vs -> global.
// ---------------------------------------------------------------------------
__global__ __launch_bounds__(512) void node_fusedC_kernel(
        const unsigned short* __restrict__ U, const unsigned short* __restrict__ Hs,
        const unsigned short* __restrict__ Wp2b, const float* __restrict__ b2bs,
        const unsigned short* __restrict__ Wp3a, const float* __restrict__ b3a,
        const unsigned short* __restrict__ Wp3b, const float* __restrict__ b3b,
        const unsigned short* __restrict__ Wp4r, const float* __restrict__ b4ap,
        const unsigned short* __restrict__ Wp4s,
        unsigned short* __restrict__ C4, unsigned short* __restrict__ Vs) {
    __shared__ __align__(16) unsigned short buf0[16 * 264];
    __shared__ __align__(16) unsigned short buf1[16 * 264];
    const int m0 = blockIdx.x * 16;
    const int tid  = threadIdx.x;
    const int wave = tid >> 6;
    const int lane = tid & 63;
    const int l15  = lane & 15;
    const int quad = lane >> 4;
    const int n0   = wave * 32;
    const int koff = quad * 8;

    // ---- S0: colsum -> buf1 (Ssc rows local 0..15) ----
    {
        const int rl = tid >> 5;           // group 0..15
        const int ct = (tid & 31) * 8;     // 8 cols
        const int g = m0 + rl;
        const int b = g / 100, i = g - b * 100;
        float u[8], s[8];
        {
            ushort4v u0 = *(const ushort4v*)(U + (size_t)g * 256 + ct);
            ushort4v u1 = *(const ushort4v*)(U + (size_t)g * 256 + ct + 4);
            #pragma unroll
            for (int e = 0; e < 4; ++e) { u[e] = bf2f(u0[e]); u[4 + e] = bf2f(u1[e]); }
            #pragma unroll
            for (int e = 0; e < 8; ++e) s[e] = 0.f;
        }
        const unsigned short* base = Hs + (size_t)b * 100 * 256 + ct;
        #pragma unroll 5
        for (int j = 0; j < 100; ++j) {
            ushort4v h0 = *(const ushort4v*)(base + (size_t)j * 256);
            ushort4v h1 = *(const ushort4v*)(base + (size_t)j * 256 + 4);
            #pragma unroll
            for (int e = 0; e < 4; ++e) {
                float v0 = u[e] + bf2f(h0[e]);     s[e]     += (v0 > 0.f ? v0 : 0.f);
                float v1 = u[4 + e] + bf2f(h1[e]); s[4 + e] += (v1 > 0.f ? v1 : 0.f);
            }
        }
        {
            ushort4v h0 = *(const ushort4v*)(base + (size_t)i * 256);
            ushort4v h1 = *(const ushort4v*)(base + (size_t)i * 256 + 4);
            #pragma unroll
            for (int e = 0; e < 4; ++e) {
                float v0 = u[e] + bf2f(h0[e]);     s[e]     -= (v0 > 0.f ? v0 : 0.f);
                float v1 = u[4 + e] + bf2f(h1[e]); s[4 + e] -= (v1 > 0.f ? v1 : 0.f);
            }
        }
        uint4v d;
        d[0] = f2bf_pk(s[0] * 0.01f, s[1] * 0.01f);
        d[1] = f2bf_pk(s[2] * 0.01f, s[3] * 0.01f);
        d[2] = f2bf_pk(s[4] * 0.01f, s[5] * 0.01f);
        d[3] = f2bf_pk(s[6] * 0.01f, s[7] * 0.01f);
        *(uint4v*)(&buf1[rl * 264 + ct]) = d;
    }
    __syncthreads();

    // ---- S1: vin = Ssc@W2b + b2bs -> buf0 ----
    {
        float4v acc[2];
        acc[0] = (float4v)(0.0f); acc[1] = (float4v)(0.0f);
        for (int kb = 0; kb < 8; ++kb) {
            short8 af = *(const short8*)(&buf1[l15 * 264 + kb * 32 + koff]);
            #pragma unroll
            for (int ni = 0; ni < 2; ++ni) {
                short8 bf = *(const short8*)(Wp2b + ((size_t)kb * 256 + n0 + ni * 16 + l15) * 32 + koff);
                acc[ni] = __builtin_amdgcn_mfma_f32_16x16x32_bf16(af, bf, acc[ni], 0, 0, 0);
            }
        }
        #pragma unroll
        for (int ni = 0; ni < 2; ++ni) {
            int col = n0 + ni * 16 + l15;
            float bv = b2bs[col];
            #pragma unroll
            for (int r = 0; r < 4; ++r)
                buf0[(quad * 4 + r) * 264 + col] = f2bf(acc[ni][r] + bv);
        }
    }
    __syncthreads();

    // ---- S2: t3 = relu(vin@W3a + b3a) -> buf1 ----
    {
        float4v acc[2];
        acc[0] = (float4v)(0.0f); acc[1] = (float4v)(0.0f);
        for (int kb = 0; kb < 8; ++kb) {
            short8 af = *(const short8*)(&buf0[l15 * 264 + kb * 32 + koff]);
            #pragma unroll
            for (int ni = 0; ni < 2; ++ni) {
                short8 bf = *(const short8*)(Wp3a + ((size_t)kb * 256 + n0 + ni * 16 + l15) * 32 + koff);
                acc[ni] = __builtin_amdgcn_mfma_f32_16x16x32_bf16(af, bf, acc[ni], 0, 0, 0);
            }
        }
        __syncthreads();   // buf1's S1 readers done; safe rewrite
        #pragma unroll
        for (int ni = 0; ni < 2; ++ni) {
            int col = n0 + ni * 16 + l15;
            float bv = b3a[col];
            #pragma unroll
            for (int r = 0; r < 4; ++r) {
                float v = acc[ni][r] + bv;
                v = v > 0.f ? v : 0.f;
                buf1[(quad * 4 + r) * 264 + col] = f2bf(v);
            }
        }
    }
    __syncthreads();

    // ---- S3: v2 = t3@W3b + b3b -> buf0 ----
    {
        float4v acc[2];
        acc[0] = (float4v)(0.0f); acc[1] = (float4v)(0.0f);
        for (int kb = 0; kb < 8; ++kb) {
            short8 af = *(const short8*)(&buf1[l15 * 264 + kb * 32 + koff]);
            #pragma unroll
            for (int ni = 0; ni < 2; ++ni) {
                short8 bf = *(const short8*)(Wp3b + ((size_t)kb * 256 + n0 + ni * 16 + l15) * 32 + koff);
                acc[ni] = __builtin_amdgcn_mfma_f32_16x16x32_bf16(af, bf, acc[ni], 0, 0, 0);
            }
        }
        __syncthreads();   // buf0's S2 readers done; safe rewrite
        #pragma unroll
        for (int ni = 0; ni < 2; ++ni) {
            int col = n0 + ni * 16 + l15;
            float bv = b3b[col];
            #pragma unroll
            for (int r = 0; r < 4; ++r)
                buf0[(quad * 4 + r) * 264 + col] = f2bf(acc[ni][r] + bv);
        }
    }
    __syncthreads();

    // ---- S4 (dual): C4 = v2@W4r + b4ap ; Vs = v2@W4s ----
    {
        float4v aC[2], aV[2];
        aC[0] = (float4v)(0.0f); aC[1] = (float4v)(0.0f);
        aV[0] = (float4v)(0.0f); aV[1] = (float4v)(0.0f);
        for (int kb = 0; kb < 8; ++kb) {
            short8 af = *(const short8*)(&buf0[l15 * 264 + kb * 32 + koff]);
            #pragma unroll
            for (int ni = 0; ni < 2; ++ni) {
                short8 bc = *(const short8*)(Wp4r + ((size_t)kb * 256 + n0 + ni * 16 + l15) * 32 + koff);
                short8 bv = *(const short8*)(Wp4s + ((size_t)kb * 256 + n0 + ni * 16 + l15) * 32 + koff);
                aC[ni] = __builtin_amdgcn_mfma_f32_16x16x32_bf16(af, bc, aC[ni], 0, 0, 0);
                aV[ni] = __builtin_amdgcn_mfma_f32_16x16x32_bf16(af, bv, aV[ni], 0, 0, 0);
            }
        }
        #pragma unroll
        for (int ni = 0; ni < 2; ++ni) {
            int col = n0 + ni * 16 + l15;
            float bv = b4ap[col];
            #pragma unroll
            for (int r = 0; r < 4; ++r) {
                size_t o = (size_t)(m0 + quad * 4 + r) * 256 + col;
                C4[o] = f2bf(aC[ni][r] + bv);
                Vs[o] = f2bf(aV[ni][r]);
            }
        }
    }
}

// ---------------------------------------------------------------------------
// Phase B: grid (155,32), block 512 (8 waves x 32 cols, EVEN/ODD pairing).
// EDGE-LINEAR. Block (t,b) owns flat edges e0=t*64..+63 of batch b; nr spans
// <=2 values (split row br). Threshold j: j = jb + row - 100*(row>=br)
// + (row>=bd0) + (row>=bd1), jb/br/bd0/bd1 block-uniform. Prefetch of 16 Vs
// dwords + C4 issued BEFORE stage0 (no asm pin; __syncthreads fences them,
// latency hides under stage0 Hs reads). stage0: wave-uniform U branch.
// K-loop: acc[4][2] vs permuted Wpz, pointer-bump, UNROLL 2. z4: f32 C4
// selects, reg-only. Projection waves 0-3 vs Wfp. LDS 33792 B. (512,6).
// Spill guard: WRITE_SIZE ~4950 KB.
// ---------------------------------------------------------------------------
__global__ __launch_bounds__(512, 6) void edge_phaseB_kernel(
        const unsigned short* __restrict__ Hs, const unsigned short* __restrict__ Vs,
        const unsigned short* __restrict__ U, const unsigned short* __restrict__ C4,
        const unsigned short* __restrict__ Wpz, const unsigned short* __restrict__ Wfp,
        const float* __restrict__ bfv,
        float* __restrict__ out) {
    __shared__ __align__(16) unsigned short t2s[64 * 264]; // 33792 B (z4 aliases later)
    const int e0 = blockIdx.x * 64;           // first flat edge of tile
    const int b  = blockIdx.y;
    const int nE = (9900 - e0) < 64 ? (9900 - e0) : 64;   // 64 (or 44 last tile)
    const int nr0 = e0 / 99;                  // receiver of first edge
    const int nr1c = (nr0 < 99) ? nr0 + 1 : 99;           // clamped (load safety)
    const int br  = (nr0 + 1) * 99 - e0;      // local row where receiver -> nr1
    const int bd0 = 100 * nr0 - e0;           // diagonal threshold, section 0
    const int bd1 = bd0 + 100;                // diagonal threshold, section 1
    const int jb  = e0 - 99 * nr0;            // base k of section 0
    const unsigned ub100 = (unsigned)(b * 100);
    const int tid  = threadIdx.x;
    const int wave = tid >> 6;          // 0..7
    const int lane = tid & 63;
    const int l15  = lane & 15;
    const int quad = lane >> 4;
    const int n0   = wave * 32;         // 32-col slice per wave
    const int koff = quad * 8;
    const int cp = n0 + 2 * l15;        // even col; odd = cp+1
    const int rbase = quad * 4;         // row offset within each mi-tile

    // ---- early prefetch: 16 Vs dwords + 2 C4 dwords. Issued BEFORE stage0;
    //      the __syncthreads below fences them, so the compiler's pre-barrier
    //      vmcnt(0) drains them in parallel with stage0's Hs loads. ----
    unsigned int vsp[16];
    #pragma unroll
    for (int mi = 0; mi < 4; ++mi) {
        #pragma unroll
        for (int r = 0; r < 4; ++r) {
            int row = mi * 16 + rbase + r;
            int jj = jb + row - ((row >= br) ? 100 : 0)
                   + ((row >= bd0) ? 1 : 0) + ((row >= bd1) ? 1 : 0);
            vsp[mi * 4 + r] =
                *(const unsigned int*)(Vs + ((ub100 + (unsigned)jj) << 8) + (unsigned)cp);
        }
    }
    unsigned int c4a = *(const unsigned int*)(C4 + ((ub100 + (unsigned)nr0) << 8) + (unsigned)cp);
    unsigned int c4b = *(const unsigned int*)(C4 + ((ub100 + (unsigned)nr1c) << 8) + (unsigned)cp);
    float c4e0 = bf2f((unsigned short)c4a);
    float c4o0 = bf2f((unsigned short)(c4a >> 16));
    float c4e1 = bf2f((unsigned short)c4b);
    float c4o1 = bf2f((unsigned short)(c4b >> 16));

    // ---- stage 0: build t2 tile (8 rows/wave; wave-uniform j + U branch) ----
    {
        const int c = lane * 4;
        ushort4v uva = *(const ushort4v*)(U + ((ub100 + (unsigned)nr0) << 8) + c);
        ushort4v uvb = *(const ushort4v*)(U + ((ub100 + (unsigned)nr1c) << 8) + c);
        float ua0 = bf2f(uva[0]), ua1 = bf2f(uva[1]), ua2 = bf2f(uva[2]), ua3 = bf2f(uva[3]);
        float ub0 = bf2f(uvb[0]), ub1 = bf2f(uvb[1]), ub2 = bf2f(uvb[2]), ub3 = bf2f(uvb[3]);
        for (int r = wave; r < 64; r += 8) {
            // wave-uniform threshold j:
            int sec = (r >= br) ? 1 : 0;
            int j = jb + r - (sec ? 100 : 0) + ((r >= bd0) ? 1 : 0) + ((r >= bd1) ? 1 : 0);
            ushort4v hv = *(const ushort4v*)(Hs + ((ub100 + (unsigned)j) << 8) + c);
            float t0, t1, t2, t3;
            if (sec) {            // wave-uniform branch, no cndmask
                t0 = ub0 + bf2f(hv[0]); t1 = ub1 + bf2f(hv[1]);
                t2 = ub2 + bf2f(hv[2]); t3 = ub3 + bf2f(hv[3]);
            } else {
                t0 = ua0 + bf2f(hv[0]); t1 = ua1 + bf2f(hv[1]);
                t2 = ua2 + bf2f(hv[2]); t3 = ua3 + bf2f(hv[3]);
            }
            t0 = t0 > 0.f ? t0 : 0.f;
            t1 = t1 > 0.f ? t1 : 0.f;
            t2 = t2 > 0.f ? t2 : 0.f;
            t3 = t3 > 0.f ? t3 : 0.f;
            uint2v p;
            p[0] = f2bf_pk(t0, t1);
            p[1] = f2bf_pk(t2, t3);
            *(uint2v*)(&t2s[r * 264 + c]) = p;
        }
    }
    __syncthreads();

    // ---- K-loop: z4 GEMM (K=256); acc init = 0 (C4 added in z4) ----
    float4v acc[4][2];
    #pragma unroll
    for (int mi = 0; mi < 4; ++mi) {
        acc[mi][0] = (float4v)(0.0f);
        acc[mi][1] = (float4v)(0.0f);
    }

    const unsigned short* wz = Wpz + (((unsigned)(n0 + l15)) << 5) + (unsigned)koff;
    const unsigned short* a0 = t2s + l15 * 264 + koff;
    #pragma unroll 2              // acc=32 regs; 2-iter live window fits ~85 cap
    for (int kb = 0; kb < 8; ++kb) {
        short8 bf0 = *(const short8*)(wz);
        short8 bf1 = *(const short8*)(wz + 512);     // +16 packed cols
        #pragma unroll
        for (int mi = 0; mi < 4; ++mi) {
            short8 af = *(const short8*)(a0 + mi * 16 * 264 + kb * 32);
            acc[mi][0] = __builtin_amdgcn_mfma_f32_16x16x32_bf16(af, bf0, acc[mi][0], 0, 0, 0);
            acc[mi][1] = __builtin_amdgcn_mfma_f32_16x16x32_bf16(af, bf1, acc[mi][1], 0, 0, 0);
        }
        wz += 8192;               // next K-block (256 packed cols * 32)
    }
    __syncthreads();            // all t2s A-reads done; z4 aliases t2s below

    // ---- z4 = relu(C4_nr + Vs_j + acc) -> LDS (natural order, reg-only) ----
    #pragma unroll
    for (int mi = 0; mi < 4; ++mi) {
        #pragma unroll
        for (int r = 0; r < 4; ++r) {
            int row = mi * 16 + rbase + r;      // local edge idx (C-layout)
            unsigned int vp = vsp[mi * 4 + r];
            float ce = (row >= br) ? c4e1 : c4e0;
            float co = (row >= br) ? c4o1 : c4o0;
            float z0 = bf2f((unsigned short)vp) + ce + acc[mi][0][r];
            float z1 = bf2f((unsigned short)(vp >> 16)) + co + acc[mi][1][r];
            z0 = z0 > 0.f ? z0 : 0.f;
            z1 = z1 > 0.f ? z1 : 0.f;
            *(unsigned int*)(&t2s[row * 264 + cp]) = f2bf_pk(z0, z1);
        }
    }
    __syncthreads();

    // ---- projection: waves 0-3, rows wave*16..+15; 8 MFMA vs Wfp ----
    if (wave < 4) {
        float4v pacc = (float4v)(0.0f);
        const unsigned short* za0 = t2s + (wave * 16 + l15) * 264 + koff;
        const unsigned short* wf0 = Wfp + (unsigned)(l15 * 32 + koff);
        #pragma unroll
        for (int kb = 0; kb < 8; ++kb) {
            short8 za = *(const short8*)(za0 + kb * 32);
            short8 wb = *(const short8*)(wf0 + kb * 512);
            pacc = __builtin_amdgcn_mfma_f32_16x16x32_bf16(za, wb, pacc, 0, 0, 0);
        }
        if (l15 < 4) {
            float bv = bfv[l15];
            #pragma unroll
            for (int r = 0; r < 4; ++r) {
                int row = wave * 16 + rbase + r;
                if (row < nE)
                    out[(unsigned)((b * 9900 + e0 + row) * 4 + l15)] = pacc[r] + bv;
            }
        }
    }
}

extern "C" void kernel_launch(void* const* d_in, const int* in_sizes, int n_in,
                              void* d_out, int out_size, void* d_ws, size_t ws_size,
                              hipStream_t stream) {
    const float* x   = (const float*)d_in[0];
    const float* w1a = (const float*)d_in[3];
    const float* b1a = (const float*)d_in[4];
    const float* w1b = (const float*)d_in[5];
    const float* b1b = (const float*)d_in[6];
    const float* w2a = (const float*)d_in[7];
    const float* b2a = (const float*)d_in[8];
    const float* w2b = (const float*)d_in[9];
    const float* b2b = (const float*)d_in[10];
    const float* w3a = (const float*)d_in[11];
    const float* b3a = (const float*)d_in[12];
    const float* w3b = (const float*)d_in[13];
    const float* b3b = (const float*)d_in[14];
    const float* w4a = (const float*)d_in[15];
    const float* b4a = (const float*)d_in[16];
    const float* w4b = (const float*)d_in[17];
    const float* b4b = (const float*)d_in[18];
    const float* wo  = (const float*)d_in[19];
    const float* bo  = (const float*)d_in[20];
    float* out = (float*)d_out;
    (void)in_sizes; (void)n_in; (void)out_size; (void)ws_size;

    char* ws = (char*)d_ws;
    size_t off = 0;
    auto alloc = [&](size_t bytes) {
        size_t o = off;
        off = (off + bytes + 255) & ~(size_t)255;
        return o;
    };
    const size_t SLOT_BF = (size_t)3200 * 256 * 2;   // 1.64 MB
    unsigned short* S_U  = (unsigned short*)(ws + alloc(SLOT_BF)); // U
    unsigned short* S_Hs = (unsigned short*)(ws + alloc(SLOT_BF)); // Hs
    unsigned short* S_Vs = (unsigned short*)(ws + alloc(SLOT_BF)); // Vs
    unsigned short* S_4  = (unsigned short*)(ws + alloc(SLOT_BF)); // hin -> C4
    unsigned short* Wp1a = (unsigned short*)(ws + alloc(224 * 256 * 2));
    unsigned short* Wp1b = (unsigned short*)(ws + alloc(256 * 256 * 2));
    unsigned short* Wp2r = (unsigned short*)(ws + alloc(256 * 256 * 2));
    unsigned short* Wp2s = (unsigned short*)(ws + alloc(256 * 256 * 2));
    unsigned short* Wp2b = (unsigned short*)(ws + alloc(256 * 256 * 2));
    unsigned short* Wp3a = (unsigned short*)(ws + alloc(256 * 256 * 2));
    unsigned short* Wp3b = (unsigned short*)(ws + alloc(256 * 256 * 2));
    unsigned short* Wp4r = (unsigned short*)(ws + alloc(256 * 256 * 2));
    unsigned short* Wp4s = (unsigned short*)(ws + alloc(256 * 256 * 2));
    unsigned short* Wpz  = (unsigned short*)(ws + alloc(256 * 256 * 2));
    unsigned short* Wfp  = (unsigned short*)(ws + alloc(8 * 16 * 32 * 2));
    float*          bfv  = (float*)(ws + alloc(4 * 4));
    float*          b4ap = (float*)(ws + alloc(256 * 4));
    float*          b2bs = (float*)(ws + alloc(256 * 4));
    // total ~8 MB (<= 11.2 proven safe)

    unsigned short* hin = S_4;   // [prep, nodeA]
    unsigned short* C4  = S_4;   // [nodeC, phaseB]

    // ---- 4 dispatches ----
    hipLaunchKernelGGL(prep_kernel, dim3(5330), dim3(256), 0, stream,
                       x, w1a, w1b, w2a, w2b, w3a, w3b, w4a, b4a, w4b, b4b, wo, bo, b2b,
                       Wp1a, Wp1b, Wp2r, Wp2s, Wp2b, Wp3a, Wp3b, Wp4r, Wp4s, Wpz,
                       Wfp, bfv, b4ap, b2bs, hin);
    hipLaunchKernelGGL(node_fusedA_kernel, dim3(200), dim3(512), 0, stream,
                       hin, Wp1a, b1a, Wp1b, b1b, Wp2r, b2a, Wp2s, S_U, S_Hs);
    hipLaunchKernelGGL(node_fusedC_kernel, dim3(200), dim3(512), 0, stream,
                       S_U, S_Hs, Wp2b, b2bs, Wp3a, b3a, Wp3b, b3b, Wp4r, b4ap, Wp4s, C4, S_Vs);
    hipLaunchKernelGGL(edge_phaseB_kernel, dim3(155, 32), dim3(512), 0, stream,
                       S_Hs, S_Vs, S_U, C4, Wpz, Wfp, bfv, out);
}